// Round 11
// baseline (90.600 us; speedup 1.0000x reference)
//
#include <hip/hip_runtime.h>
#include <hip/hip_bf16.h>
#include <math.h>

#define B_ 8
#define H_ 128
#define W_ 128
#define C_ 3
#define D_ 132
#define HW_ (H_*W_)            // 16384
#define RPB_ (HW_+1)           // 16385 rows per batch (incl. zero row)
#define NROWS_ (B_*RPB_)       // 131080
#define AROWS_ 131136
#define FSTRIDE_ 136           // bf16 row stride for flat_ext AND z_ext (272 B)
#define MSTRIDE_ 168           // M row stride: 336 B -> 2-way LDS slots (free)
#define MROWS_ 136             // real M rows 0..135
#define MELEMS_ (MROWS_*MSTRIDE_)   // 22848 real elems
#define MALLOC_ 23040               // padded to 45 KiB (45 x 1KiB chunks)
#define NK_ 65536
#define NOUT_ (B_*NK_)         // 524288

typedef __attribute__((ext_vector_type(8))) short short8v;
typedef __attribute__((ext_vector_type(8))) unsigned short ushort8v;
typedef __attribute__((ext_vector_type(4))) float f32x4;

#define GLOAD16(gp, lp) __builtin_amdgcn_global_load_lds( \
  (const __attribute__((address_space(1))) unsigned int*)(gp), \
  (__attribute__((address_space(3))) unsigned int*)(void*)(lp), 16, 0, 0)

__device__ inline float bf2f(unsigned short u) {
  return __uint_as_float(((unsigned)u) << 16);
}
__device__ inline unsigned short f2bf(float f) {
  __hip_bfloat16 hb = __float2bfloat16(f);
  return *(unsigned short*)&hb;
}

// ---------------------------------------------------------------------------
// K0: M_bf16 [136][168]: a<132 -> Ks^T Qs; a==132 -> u (su row);
// a==133 -> v (sv row); else 0. Cols >=132 zero; pad elems 22848..23040 zero.
// c = ks_b . qs_b.
// ---------------------------------------------------------------------------
__global__ __launch_bounds__(512) void prep_kernel(
    const float* __restrict__ ks_w, const float* __restrict__ ks_b,
    const float* __restrict__ qs_w, const float* __restrict__ qs_b,
    unsigned short* __restrict__ Mb, float* __restrict__ cc) {
  int idx = blockIdx.x * 512 + threadIdx.x;
  if (idx >= MALLOC_) return;
  float val = 0.f;
  if (idx < MELEMS_) {
    int a = idx / MSTRIDE_;
    int k = idx - a * MSTRIDE_;
    if (k < D_) {
      if (a < D_) {
        for (int o = 0; o < D_; ++o)
          val = fmaf(ks_w[o * D_ + a], qs_w[o * D_ + k], val);
      } else if (a == 132) {
        for (int o = 0; o < D_; ++o)
          val = fmaf(qs_b[o], ks_w[o * D_ + k], val);
      } else if (a == 133) {
        for (int o = 0; o < D_; ++o)
          val = fmaf(ks_b[o], qs_w[o * D_ + k], val);
      }
    }
  }
  Mb[idx] = f2bf(val);
  if (idx == 0) {
    float s = 0.f;
    for (int o = 0; o < D_; ++o) s = fmaf(ks_b[o], qs_b[o], s);
    cc[0] = s;
  }
}

// ---------------------------------------------------------------------------
// conv helper: one (d, w0) item -> 16 conv outputs + partial ssq
// ---------------------------------------------------------------------------
__device__ __forceinline__ float conv_item16(
    const float* __restrict__ in_s, const float* __restrict__ w_s,
    float bias, int d, int w0, float* acc) {
  float wt[27];
#pragma unroll
  for (int j = 0; j < 27; ++j) wt[j] = w_s[d * 27 + j];
#pragma unroll
  for (int i = 0; i < 16; ++i) acc[i] = bias;
#pragma unroll
  for (int ck = 0; ck < 9; ++ck) {
    const float4* p4 = (const float4*)(in_s + ck * 132);
    float v[20];
#pragma unroll
    for (int j = 0; j < 5; ++j) {
      float4 t4 = p4[(w0 >> 2) + j];   // wave-broadcast reads
      v[4 * j + 0] = t4.x; v[4 * j + 1] = t4.y;
      v[4 * j + 2] = t4.z; v[4 * j + 3] = t4.w;
    }
#pragma unroll
    for (int i = 0; i < 16; ++i) {
      float a0 = fmaf(v[i], wt[ck * 3 + 0], acc[i]);
      float a1 = fmaf(v[i + 1], wt[ck * 3 + 1], a0);
      acc[i] = fmaf(v[i + 2], wt[ck * 3 + 2], a1);
    }
  }
  float ssq = 0.f;
#pragma unroll
  for (int i = 0; i < 16; ++i) ssq = fmaf(acc[i], acc[i], ssq);
  return ssq;
}

// ---------------------------------------------------------------------------
// K1 fused conv+gemm (round-10 structure; M stride 168 kills the 8-way
// bank conflict on phase-C B-reads).
// LDS: Ms 46080 + nscale 528 + un 34880 = 81488 <= 81920 -> 2 blocks/CU.
// Phase-C reads of M rows 136..143 (ct=8, c15>=8) spill past Ms into
// nscale/un: garbage, but those lanes' outputs (cols 137..143) are discarded
// and col 136 writes a constant.
// ---------------------------------------------------------------------------
__global__ __launch_bounds__(512, 4) void fused_conv_gemm_kernel(
    const float* __restrict__ img, const float* __restrict__ cw,
    const float* __restrict__ cb, unsigned short* __restrict__ fb,
    const unsigned short* __restrict__ Mb, const float* __restrict__ cc,
    unsigned short* __restrict__ zb) {
  int bid = blockIdx.x;
  int tid = threadIdx.x;

  if (bid == B_ * H_) {
    // zero row 16384 of every batch
    float cval = cc[0];
    for (int i = tid; i < B_ * FSTRIDE_; i += 512) {
      int b = i / FSTRIDE_, d = i - (i / FSTRIDE_) * FSTRIDE_;
      size_t r = (size_t)b * RPB_ + HW_;
      fb[r * FSTRIDE_ + d] = (d == 132) ? 0x3F80 : 0;     // [0 x132, 1, su=0, 0, 0]
      unsigned short zv = 0;
      if (d == 132) zv = f2bf(cval);                      // sv+c = c
      else if (d == 133) zv = 0x3F80;                     // 1.0
      zb[r * FSTRIDE_ + d] = zv;
    }
    return;
  }

  int wave = tid >> 6, lane = tid & 63;
  __shared__ __align__(16) unsigned short Ms[MALLOC_];   // 46080 B (45 chunks)
  __shared__ float nscale[132];                          // 528 B
  __shared__ __align__(16) char un[34880];               // union region
  float* in_s = (float*)un;            // 9*132
  float* w_s  = in_s + 9 * 132;        // 132*27
  float* b_s  = w_s + 132 * 27;        // 132
  float* parts = b_s + 132;            // 8*132   (23760 B < 34880)
  unsigned short* As = (unsigned short*)un;  // [128][136] + 32 pad (restage)

  // stage M (45 KiB) - drained by the phase-A barrier
  for (int ch = wave; ch < 45; ch += 8)
    GLOAD16(Mb + (size_t)ch * 512 + lane * 8, Ms + ch * 512);

  int b = bid >> 7, h = bid & 127;
  for (int i = tid; i < 9 * 132; i += 512) {
    int ck = i / 132, x = i - ck * 132;
    int c = ck / 3, kh = ck - c * 3;
    int hh = h + kh - 1, ww = x - 1;
    float val = 0.f;
    if (x >= 1 && x <= 128 && hh >= 0 && hh < H_)
      val = img[((size_t)(b * C_ + c) * H_ + hh) * W_ + ww];
    in_s[i] = val;
  }
  for (int i = tid; i < D_ * 27; i += 512) w_s[i] = cw[i];
  if (tid < D_) b_s[tid] = cb[tid];
  __syncthreads();

  // phase A: conv. Items {tid, tid+512, tid+1024 if tid<32}, 16-wide each.
  float acc0[16], acc1[16], acc2[16];
  int i0 = tid, i1 = tid + 512;
  int wg0 = i0 / 132, dd0 = i0 - wg0 * 132;
  int wg1 = i1 / 132, dd1 = i1 - wg1 * 132;
  parts[wg0 * 132 + dd0] = conv_item16(in_s, w_s, b_s[dd0], dd0, wg0 * 16, acc0);
  parts[wg1 * 132 + dd1] = conv_item16(in_s, w_s, b_s[dd1], dd1, wg1 * 16, acc1);
  int dd2 = 0;
  if (tid < 32) {
    dd2 = 100 + tid;                    // i2 = tid+1024 -> wg 7, d 100..131
    parts[7 * 132 + dd2] = conv_item16(in_s, w_s, b_s[dd2], dd2, 112, acc2);
  }
  __syncthreads();
  if (tid < 132) {
    float s = 0.f;
#pragma unroll
    for (int rr = 0; rr < 8; ++rr) s += parts[rr * 132 + tid];
    nscale[tid] = 1.f / fmaxf(sqrtf(s), 1e-12f);
  }
  __syncthreads();

  // phase B: store flat_ext to GLOBAL only (coalesced per-wave: lanes = d)
  size_t rowbase = (size_t)b * RPB_ + (size_t)h * W_;
  {
    float sc = nscale[dd0];
#pragma unroll
    for (int i = 0; i < 16; ++i)
      fb[(rowbase + wg0 * 16 + i) * FSTRIDE_ + dd0] = f2bf(acc0[i] * sc);
    sc = nscale[dd1];
#pragma unroll
    for (int i = 0; i < 16; ++i)
      fb[(rowbase + wg1 * 16 + i) * FSTRIDE_ + dd1] = f2bf(acc1[i] * sc);
  }
  if (tid < 32) {
    float sc = nscale[dd2];
#pragma unroll
    for (int i = 0; i < 16; ++i)
      fb[(rowbase + 112 + i) * FSTRIDE_ + dd2] = f2bf(acc2[i] * sc);
  }
  if (tid < 128) {  // row tails: cols 132..135 = [1.0, 0, 0, 0]
    uint2 tv; tv.x = 0x3F80u; tv.y = 0u;
    *(uint2*)&fb[(rowbase + tid) * FSTRIDE_ + 132] = tv;   // col133 su written in C
  }
  __syncthreads();  // drains global stores -> L2-visible; un now dead

  // restage this block's 128 fb rows into As via global_load_lds (L2-hot)
  const unsigned short* Ag = fb + rowbase * FSTRIDE_;
  for (int ch = wave; ch < 34; ch += 8)
    GLOAD16(Ag + (size_t)ch * 512 + lane * 8, As + ch * 512);
  if (tid < 32) As[128 * FSTRIDE_ + tid] = 0;  // wrap pad for K-slice 5
  __syncthreads();

  // phase C: MFMA. wave w: rows w*16..w*16+15, 9 col-tiles, K = 5 slices.
  int c15 = lane & 15, kg = lane >> 4;
  const unsigned short* arow = As + (wave * 16 + c15) * FSTRIDE_ + kg * 8;
  const unsigned short* brow = Ms + c15 * MSTRIDE_ + kg * 8;
  f32x4 acc[9] = {};
#pragma unroll
  for (int ks = 0; ks < 5; ++ks) {
    short8v af = *(const short8v*)(arow + ks * 32);
#pragma unroll
    for (int ct = 0; ct < 9; ++ct) {
      short8v bf = *(const short8v*)(brow + ct * 16 * MSTRIDE_ + ks * 32);
      acc[ct] = __builtin_amdgcn_mfma_f32_16x16x32_bf16(af, bf, acc[ct], 0, 0, 0);
    }
  }
  float cval = cc[0];
  size_t rbase = rowbase + wave * 16 + kg * 4;   // global row (incl. zero rows)
#pragma unroll
  for (int ct = 0; ct < 9; ++ct) {
    int col = ct * 16 + c15;
#pragma unroll
    for (int j = 0; j < 4; ++j) {
      size_t r = rbase + j;
      if (col < D_)            zb[r * FSTRIDE_ + col] = f2bf(acc[ct][j]);
      else if (col == 132)     fb[r * FSTRIDE_ + 133] = f2bf(acc[ct][j]);        // su
      else if (col == 133)     zb[r * FSTRIDE_ + 132] = f2bf(acc[ct][j] + cval); // sv+c
      else if (col == 134)     zb[r * FSTRIDE_ + 133] = 0x3F80;                  // 1.0
      else if (col == 135)     zb[r * FSTRIDE_ + 134] = 0;
      else if (col == 136)     zb[r * FSTRIDE_ + 135] = 0;
    }
  }
}

// ---------------------------------------------------------------------------
// K3: gather + dot. XCD batch-affinity (b = blockIdx & 7) + 2 outputs per
// thread WITHIN the same batch (rem, rem+32768) for 2x memory-level
// parallelism without breaking L2 locality (round-6 lesson).
// ---------------------------------------------------------------------------
__global__ __launch_bounds__(256) void gather_kernel(
    const int* __restrict__ xi, const int* __restrict__ yi,
    const unsigned short* __restrict__ flat, const unsigned short* __restrict__ zb,
    float* __restrict__ out) {
  const float scale = 0.08703882797784892f;  // 132^-0.5
  int bi = blockIdx.x;                 // [0, 8192)
  int b = bi & 7;
  int chunk = bi >> 3;                 // [0, 1024)
  int lane = threadIdx.x & 7;
  int rem1 = chunk * 32 + (threadIdx.x >> 3);
  int rem2 = rem1 + 32768;             // same batch

  size_t ib1 = (size_t)b * NK_ + rem1;
  size_t ib2 = (size_t)b * NK_ + rem2;
  int x1 = xi[ib1], y1 = yi[ib1];
  int x2 = xi[ib2], y2 = yi[ib2];
  size_t bbase = (size_t)b * RPB_;
  const unsigned short* fx1 = flat + (bbase + x1) * FSTRIDE_;
  const unsigned short* zy1 = zb + (bbase + y1) * FSTRIDE_;
  const unsigned short* fx2 = flat + (bbase + x2) * FSTRIDE_;
  const unsigned short* zy2 = zb + (bbase + y2) * FSTRIDE_;

  int e0 = lane * 8, e1 = 64 + lane * 8;
  ushort8v a10 = *(const ushort8v*)(fx1 + e0);
  ushort8v a11 = *(const ushort8v*)(fx1 + e1);
  ushort8v z10 = *(const ushort8v*)(zy1 + e0);
  ushort8v z11 = *(const ushort8v*)(zy1 + e1);
  ushort8v a20 = *(const ushort8v*)(fx2 + e0);
  ushort8v a21 = *(const ushort8v*)(fx2 + e1);
  ushort8v z20 = *(const ushort8v*)(zy2 + e0);
  ushort8v z21 = *(const ushort8v*)(zy2 + e1);

  float acc1 = 0.f, acc2 = 0.f;
#pragma unroll
  for (int t = 0; t < 8; ++t) {
    acc1 = fmaf(bf2f(a10[t]), bf2f(z10[t]), acc1);
    acc2 = fmaf(bf2f(a20[t]), bf2f(z20[t]), acc2);
  }
#pragma unroll
  for (int t = 0; t < 8; ++t) {
    acc1 = fmaf(bf2f(a11[t]), bf2f(z11[t]), acc1);
    acc2 = fmaf(bf2f(a21[t]), bf2f(z21[t]), acc2);
  }
  if (lane == 0) {  // elems 128..135: real 128..131 + (1)(sv+c) + (su)(1) + 0s
    ushort8v a1t = *(const ushort8v*)(fx1 + 128);
    ushort8v z1t = *(const ushort8v*)(zy1 + 128);
    ushort8v a2t = *(const ushort8v*)(fx2 + 128);
    ushort8v z2t = *(const ushort8v*)(zy2 + 128);
#pragma unroll
    for (int t = 0; t < 8; ++t) {
      acc1 = fmaf(bf2f(a1t[t]), bf2f(z1t[t]), acc1);
      acc2 = fmaf(bf2f(a2t[t]), bf2f(z2t[t]), acc2);
    }
  }
  acc1 += __shfl_xor(acc1, 1);
  acc2 += __shfl_xor(acc2, 1);
  acc1 += __shfl_xor(acc1, 2);
  acc2 += __shfl_xor(acc2, 2);
  acc1 += __shfl_xor(acc1, 4);
  acc2 += __shfl_xor(acc2, 4);
  if (lane == 0) {
    out[((size_t)b << 16) | rem1] = acc1 * scale;
    out[((size_t)b << 16) | rem2] = acc2 * scale;
  }
}

// ---------------------------------------------------------------------------
extern "C" void kernel_launch(void* const* d_in, const int* in_sizes, int n_in,
                              void* d_out, int out_size, void* d_ws, size_t ws_size,
                              hipStream_t stream) {
  const int* indices  = (const int*)d_in[0];
  const float* img    = (const float*)d_in[1];
  const float* conv_w = (const float*)d_in[2];
  const float* conv_b = (const float*)d_in[3];
  const float* ks_w   = (const float*)d_in[4];
  const float* ks_b   = (const float*)d_in[5];
  const float* qs_w   = (const float*)d_in[6];
  const float* qs_b   = (const float*)d_in[7];
  float* out = (float*)d_out;

  // workspace layout (~71.4 MB)
  char* w = (char*)d_ws;
  unsigned short* flatb = (unsigned short*)w;                  // AROWS_*136 bf16
  size_t off = (size_t)AROWS_ * FSTRIDE_ * 2;
  unsigned short* zbuf = (unsigned short*)(w + off); off += (size_t)AROWS_ * FSTRIDE_ * 2;
  unsigned short* Mb = (unsigned short*)(w + off);   off += MALLOC_ * 2;
  float* cc = (float*)(w + off);

  const int* xi = indices + (size_t)B_ * NK_;      // indices[1]
  const int* yi = indices + (size_t)2 * B_ * NK_;  // indices[2]

  hipLaunchKernelGGL(prep_kernel, dim3(MALLOC_ / 512), dim3(512), 0, stream,
                     ks_w, ks_b, qs_w, qs_b, Mb, cc);
  hipLaunchKernelGGL(fused_conv_gemm_kernel, dim3(B_ * H_ + 1), dim3(512), 0, stream,
                     img, conv_w, conv_b, flatb, Mb, cc, zbuf);
  hipLaunchKernelGGL(gather_kernel, dim3(NOUT_ / 64), dim3(256), 0, stream,
                     xi, yi, flatb, zbuf, out);
}

// Round 12
// 87.718 us; speedup vs baseline: 1.0329x; 1.0329x over previous
//
#include <hip/hip_runtime.h>
#include <hip/hip_bf16.h>
#include <math.h>

#define B_ 8
#define H_ 128
#define W_ 128
#define C_ 3
#define D_ 132
#define HW_ (H_*W_)            // 16384
#define RPB_ (HW_+1)           // 16385 rows per batch (incl. zero row)
#define NROWS_ (B_*RPB_)       // 131080
#define AROWS_ 131136
#define FSTRIDE_ 136           // bf16 row stride for flat_ext AND z_ext (272 B)
#define MSTRIDE_ 168           // M row stride
#define MROWS_ 136             // real M rows 0..135
#define MELEMS_ (MROWS_*MSTRIDE_)   // 22848 real elems
#define MALLOC_ 23040               // padded to 45 KiB (45 x 1KiB chunks)
#define NK_ 65536
#define NOUT_ (B_*NK_)         // 524288

typedef __attribute__((ext_vector_type(8))) short short8v;
typedef __attribute__((ext_vector_type(8))) unsigned short ushort8v;
typedef __attribute__((ext_vector_type(4))) float f32x4;

#define GLOAD16(gp, lp) __builtin_amdgcn_global_load_lds( \
  (const __attribute__((address_space(1))) unsigned int*)(gp), \
  (__attribute__((address_space(3))) unsigned int*)(void*)(lp), 16, 0, 0)

__device__ inline float bf2f(unsigned short u) {
  return __uint_as_float(((unsigned)u) << 16);
}
__device__ inline unsigned short f2bf(float f) {
  __hip_bfloat16 hb = __float2bfloat16(f);
  return *(unsigned short*)&hb;
}

// ---------------------------------------------------------------------------
// K0: M_bf16 [136][168]: a<132 -> Ks^T Qs; a==132 -> u (su row);
// a==133 -> v (sv row); else 0. Cols >=132 zero; pad to 23040 zero.
// c = ks_b . qs_b.
// ---------------------------------------------------------------------------
__global__ __launch_bounds__(512) void prep_kernel(
    const float* __restrict__ ks_w, const float* __restrict__ ks_b,
    const float* __restrict__ qs_w, const float* __restrict__ qs_b,
    unsigned short* __restrict__ Mb, float* __restrict__ cc) {
  int idx = blockIdx.x * 512 + threadIdx.x;
  if (idx >= MALLOC_) return;
  float val = 0.f;
  if (idx < MELEMS_) {
    int a = idx / MSTRIDE_;
    int k = idx - a * MSTRIDE_;
    if (k < D_) {
      if (a < D_) {
        for (int o = 0; o < D_; ++o)
          val = fmaf(ks_w[o * D_ + a], qs_w[o * D_ + k], val);
      } else if (a == 132) {
        for (int o = 0; o < D_; ++o)
          val = fmaf(qs_b[o], ks_w[o * D_ + k], val);
      } else if (a == 133) {
        for (int o = 0; o < D_; ++o)
          val = fmaf(ks_b[o], qs_w[o * D_ + k], val);
      }
    }
  }
  Mb[idx] = f2bf(val);
  if (idx == 0) {
    float s = 0.f;
    for (int o = 0; o < D_; ++o) s = fmaf(ks_b[o], qs_b[o], s);
    cc[0] = s;
  }
}

// ---------------------------------------------------------------------------
// conv helper: one (d, w0) item -> 16 conv outputs + partial ssq
// ---------------------------------------------------------------------------
__device__ __forceinline__ float conv_item16(
    const float* __restrict__ in_s, const float* __restrict__ w_s,
    float bias, int d, int w0, float* acc) {
  float wt[27];
#pragma unroll
  for (int j = 0; j < 27; ++j) wt[j] = w_s[d * 27 + j];
#pragma unroll
  for (int i = 0; i < 16; ++i) acc[i] = bias;
#pragma unroll
  for (int ck = 0; ck < 9; ++ck) {
    const float4* p4 = (const float4*)(in_s + ck * 132);
    float v[20];
#pragma unroll
    for (int j = 0; j < 5; ++j) {
      float4 t4 = p4[(w0 >> 2) + j];   // wave-broadcast reads
      v[4 * j + 0] = t4.x; v[4 * j + 1] = t4.y;
      v[4 * j + 2] = t4.z; v[4 * j + 3] = t4.w;
    }
#pragma unroll
    for (int i = 0; i < 16; ++i) {
      float a0 = fmaf(v[i], wt[ck * 3 + 0], acc[i]);
      float a1 = fmaf(v[i + 1], wt[ck * 3 + 1], a0);
      acc[i] = fmaf(v[i + 2], wt[ck * 3 + 2], a1);
    }
  }
  float ssq = 0.f;
#pragma unroll
  for (int i = 0; i < 16; ++i) ssq = fmaf(acc[i], acc[i], ssq);
  return ssq;
}

// ---------------------------------------------------------------------------
// K1 fused conv+gemm, LDS-staged output path:
//   A: conv+norm into regs (M staged via gload_lds meanwhile)
//   B: write f (bf16) into As[128][136] (LDS only)
//   C1: vector memcpy As->fb (1KB/wave stores) ; MFMA reads As + Ms
//   [barrier: As reads retired, fb memcpy drained]
//   C2: each wave overwrites ITS OWN 16 As rows with z_ext; su -> fb col133
//   D: vector memcpy As->zb
// LDS: Ms 46080 + nscale 528 + un 34880 = 81488 <= 81920 -> 2 blocks/CU.
// Phase-C M reads of rows 136..143 (ct=8,c15>=8) spill: garbage, discarded.
// ---------------------------------------------------------------------------
__global__ __launch_bounds__(512, 4) void fused_conv_gemm_kernel(
    const float* __restrict__ img, const float* __restrict__ cw,
    const float* __restrict__ cb, unsigned short* __restrict__ fb,
    const unsigned short* __restrict__ Mb, const float* __restrict__ cc,
    unsigned short* __restrict__ zb) {
  int bid = blockIdx.x;
  int tid = threadIdx.x;

  if (bid == B_ * H_) {
    // zero row 16384 of every batch
    float cval = cc[0];
    for (int i = tid; i < B_ * FSTRIDE_; i += 512) {
      int b = i / FSTRIDE_, d = i - (i / FSTRIDE_) * FSTRIDE_;
      size_t r = (size_t)b * RPB_ + HW_;
      fb[r * FSTRIDE_ + d] = (d == 132) ? 0x3F80 : 0;     // [0 x132, 1, su=0, 0, 0]
      unsigned short zv = 0;
      if (d == 132) zv = f2bf(cval);                      // sv+c = c
      else if (d == 133) zv = 0x3F80;                     // 1.0
      zb[r * FSTRIDE_ + d] = zv;
    }
    return;
  }

  int wave = tid >> 6, lane = tid & 63;
  __shared__ __align__(16) unsigned short Ms[MALLOC_];   // 46080 B
  __shared__ float nscale[132];                          // 528 B
  __shared__ __align__(16) char un[34880];               // union region
  float* in_s = (float*)un;            // 9*132
  float* w_s  = in_s + 9 * 132;        // 132*27
  float* b_s  = w_s + 132 * 27;        // 132
  float* parts = b_s + 132;            // 8*132   (23760 B < 34880)
  unsigned short* As = (unsigned short*)un;  // [128][136] + 32 pad shorts

  // stage M (45 KiB) - drained by the phase-A barrier
  for (int ch = wave; ch < 45; ch += 8)
    GLOAD16(Mb + (size_t)ch * 512 + lane * 8, Ms + ch * 512);

  int b = bid >> 7, h = bid & 127;
  for (int i = tid; i < 9 * 132; i += 512) {
    int ck = i / 132, x = i - ck * 132;
    int c = ck / 3, kh = ck - c * 3;
    int hh = h + kh - 1, ww = x - 1;
    float val = 0.f;
    if (x >= 1 && x <= 128 && hh >= 0 && hh < H_)
      val = img[((size_t)(b * C_ + c) * H_ + hh) * W_ + ww];
    in_s[i] = val;
  }
  for (int i = tid; i < D_ * 27; i += 512) w_s[i] = cw[i];
  if (tid < D_) b_s[tid] = cb[tid];
  __syncthreads();

  // phase A: conv. Items {tid, tid+512, tid+1024 if tid<32}, 16-wide each.
  float acc0[16], acc1[16], acc2[16];
  int i0 = tid, i1 = tid + 512;
  int wg0 = i0 / 132, dd0 = i0 - wg0 * 132;
  int wg1 = i1 / 132, dd1 = i1 - wg1 * 132;
  parts[wg0 * 132 + dd0] = conv_item16(in_s, w_s, b_s[dd0], dd0, wg0 * 16, acc0);
  parts[wg1 * 132 + dd1] = conv_item16(in_s, w_s, b_s[dd1], dd1, wg1 * 16, acc1);
  int dd2 = 0;
  if (tid < 32) {
    dd2 = 100 + tid;                    // i2 = tid+1024 -> wg 7, d 100..131
    parts[7 * 132 + dd2] = conv_item16(in_s, w_s, b_s[dd2], dd2, 112, acc2);
  }
  __syncthreads();
  if (tid < 132) {
    float s = 0.f;
#pragma unroll
    for (int rr = 0; rr < 8; ++rr) s += parts[rr * 132 + tid];
    nscale[tid] = 1.f / fmaxf(sqrtf(s), 1e-12f);
  }
  __syncthreads();  // conv scratch dead; As overlay begins

  // phase B: write f (bf16) into As (LDS only; 2-way bank aliasing = free)
  {
    float sc = nscale[dd0];
#pragma unroll
    for (int i = 0; i < 16; ++i)
      As[(wg0 * 16 + i) * FSTRIDE_ + dd0] = f2bf(acc0[i] * sc);
    sc = nscale[dd1];
#pragma unroll
    for (int i = 0; i < 16; ++i)
      As[(wg1 * 16 + i) * FSTRIDE_ + dd1] = f2bf(acc1[i] * sc);
  }
  if (tid < 32) {
    float sc = nscale[dd2];
#pragma unroll
    for (int i = 0; i < 16; ++i)
      As[(112 + i) * FSTRIDE_ + dd2] = f2bf(acc2[i] * sc);
  }
  if (tid < 128) {  // row tails: cols 132..135 = [1.0, 0, 0, 0]
    uint2 tv; tv.x = 0x3F80u; tv.y = 0u;
    *(uint2*)&As[tid * FSTRIDE_ + 132] = tv;
  }
  if (tid < 32) As[128 * FSTRIDE_ + tid] = 0;  // wrap pad for K-slice 5
  __syncthreads();  // As = flat_ext tile, visible to all

  // phase C1: vector memcpy As -> fb, then MFMA (both only READ As)
  size_t rowbase = (size_t)b * RPB_ + (size_t)h * W_;
  unsigned short* fbase = fb + rowbase * FSTRIDE_;
  for (int i2 = tid; i2 < 2176; i2 += 512)
    *(ushort8v*)(fbase + i2 * 8) = *(const ushort8v*)(As + i2 * 8);

  int c15 = lane & 15, kg = lane >> 4;
  const unsigned short* arow = As + (wave * 16 + c15) * FSTRIDE_ + kg * 8;
  const unsigned short* brow = Ms + c15 * MSTRIDE_ + kg * 8;
  f32x4 acc[9] = {};
#pragma unroll
  for (int ks = 0; ks < 5; ++ks) {
    short8v af = *(const short8v*)(arow + ks * 32);
#pragma unroll
    for (int ct = 0; ct < 9; ++ct) {
      short8v bf = *(const short8v*)(brow + ct * 16 * MSTRIDE_ + ks * 32);
      acc[ct] = __builtin_amdgcn_mfma_f32_16x16x32_bf16(af, bf, acc[ct], 0, 0, 0);
    }
  }
  __syncthreads();  // all As reads retired; fb memcpy stores drained (vmcnt 0)

  // phase C2: overwrite OWN wave's 16 As rows with z_ext; su -> fb col 133
  float cval = cc[0];
  int r0 = wave * 16 + kg * 4;
#pragma unroll
  for (int ct = 0; ct < 9; ++ct) {
    int col = ct * 16 + c15;
#pragma unroll
    for (int j = 0; j < 4; ++j) {
      int r = r0 + j;
      if (col < D_)            As[r * FSTRIDE_ + col] = f2bf(acc[ct][j]);
      else if (col == 132)     fb[(rowbase + r) * FSTRIDE_ + 133] = f2bf(acc[ct][j]); // su
      else if (col == 133)     As[r * FSTRIDE_ + 132] = f2bf(acc[ct][j] + cval);      // sv+c
      else if (col == 134)     As[r * FSTRIDE_ + 133] = 0x3F80;                       // 1.0
      else if (col == 135)     As[r * FSTRIDE_ + 134] = 0;
      else if (col == 136)     As[r * FSTRIDE_ + 135] = 0;
    }
  }
  __syncthreads();  // z_ext tile complete in As

  // phase D: vector memcpy As -> zb
  unsigned short* zbase = zb + rowbase * FSTRIDE_;
  for (int i2 = tid; i2 < 2176; i2 += 512)
    *(ushort8v*)(zbase + i2 * 8) = *(const ushort8v*)(As + i2 * 8);
}

// ---------------------------------------------------------------------------
// K3: gather + dot. XCD batch-affinity (b = blockIdx & 7) + 2 outputs per
// thread within the same batch (rem, rem+32768).
// ---------------------------------------------------------------------------
__global__ __launch_bounds__(256) void gather_kernel(
    const int* __restrict__ xi, const int* __restrict__ yi,
    const unsigned short* __restrict__ flat, const unsigned short* __restrict__ zb,
    float* __restrict__ out) {
  const float scale = 0.08703882797784892f;  // 132^-0.5
  int bi = blockIdx.x;                 // [0, 8192)
  int b = bi & 7;
  int chunk = bi >> 3;                 // [0, 1024)
  int lane = threadIdx.x & 7;
  int rem1 = chunk * 32 + (threadIdx.x >> 3);
  int rem2 = rem1 + 32768;             // same batch

  size_t ib1 = (size_t)b * NK_ + rem1;
  size_t ib2 = (size_t)b * NK_ + rem2;
  int x1 = xi[ib1], y1 = yi[ib1];
  int x2 = xi[ib2], y2 = yi[ib2];
  size_t bbase = (size_t)b * RPB_;
  const unsigned short* fx1 = flat + (bbase + x1) * FSTRIDE_;
  const unsigned short* zy1 = zb + (bbase + y1) * FSTRIDE_;
  const unsigned short* fx2 = flat + (bbase + x2) * FSTRIDE_;
  const unsigned short* zy2 = zb + (bbase + y2) * FSTRIDE_;

  int e0 = lane * 8, e1 = 64 + lane * 8;
  ushort8v a10 = *(const ushort8v*)(fx1 + e0);
  ushort8v a11 = *(const ushort8v*)(fx1 + e1);
  ushort8v z10 = *(const ushort8v*)(zy1 + e0);
  ushort8v z11 = *(const ushort8v*)(zy1 + e1);
  ushort8v a20 = *(const ushort8v*)(fx2 + e0);
  ushort8v a21 = *(const ushort8v*)(fx2 + e1);
  ushort8v z20 = *(const ushort8v*)(zy2 + e0);
  ushort8v z21 = *(const ushort8v*)(zy2 + e1);

  float acc1 = 0.f, acc2 = 0.f;
#pragma unroll
  for (int t = 0; t < 8; ++t) {
    acc1 = fmaf(bf2f(a10[t]), bf2f(z10[t]), acc1);
    acc2 = fmaf(bf2f(a20[t]), bf2f(z20[t]), acc2);
  }
#pragma unroll
  for (int t = 0; t < 8; ++t) {
    acc1 = fmaf(bf2f(a11[t]), bf2f(z11[t]), acc1);
    acc2 = fmaf(bf2f(a21[t]), bf2f(z21[t]), acc2);
  }
  if (lane == 0) {  // elems 128..135: real 128..131 + (1)(sv+c) + (su)(1) + 0s
    ushort8v a1t = *(const ushort8v*)(fx1 + 128);
    ushort8v z1t = *(const ushort8v*)(zy1 + 128);
    ushort8v a2t = *(const ushort8v*)(fx2 + 128);
    ushort8v z2t = *(const ushort8v*)(zy2 + 128);
#pragma unroll
    for (int t = 0; t < 8; ++t) {
      acc1 = fmaf(bf2f(a1t[t]), bf2f(z1t[t]), acc1);
      acc2 = fmaf(bf2f(a2t[t]), bf2f(z2t[t]), acc2);
    }
  }
  acc1 += __shfl_xor(acc1, 1);
  acc2 += __shfl_xor(acc2, 1);
  acc1 += __shfl_xor(acc1, 2);
  acc2 += __shfl_xor(acc2, 2);
  acc1 += __shfl_xor(acc1, 4);
  acc2 += __shfl_xor(acc2, 4);
  if (lane == 0) {
    out[((size_t)b << 16) | rem1] = acc1 * scale;
    out[((size_t)b << 16) | rem2] = acc2 * scale;
  }
}

// ---------------------------------------------------------------------------
extern "C" void kernel_launch(void* const* d_in, const int* in_sizes, int n_in,
                              void* d_out, int out_size, void* d_ws, size_t ws_size,
                              hipStream_t stream) {
  const int* indices  = (const int*)d_in[0];
  const float* img    = (const float*)d_in[1];
  const float* conv_w = (const float*)d_in[2];
  const float* conv_b = (const float*)d_in[3];
  const float* ks_w   = (const float*)d_in[4];
  const float* ks_b   = (const float*)d_in[5];
  const float* qs_w   = (const float*)d_in[6];
  const float* qs_b   = (const float*)d_in[7];
  float* out = (float*)d_out;

  // workspace layout (~71.4 MB)
  char* w = (char*)d_ws;
  unsigned short* flatb = (unsigned short*)w;                  // AROWS_*136 bf16
  size_t off = (size_t)AROWS_ * FSTRIDE_ * 2;
  unsigned short* zbuf = (unsigned short*)(w + off); off += (size_t)AROWS_ * FSTRIDE_ * 2;
  unsigned short* Mb = (unsigned short*)(w + off);   off += MALLOC_ * 2;
  float* cc = (float*)(w + off);

  const int* xi = indices + (size_t)B_ * NK_;      // indices[1]
  const int* yi = indices + (size_t)2 * B_ * NK_;  // indices[2]

  hipLaunchKernelGGL(prep_kernel, dim3(MALLOC_ / 512), dim3(512), 0, stream,
                     ks_w, ks_b, qs_w, qs_b, Mb, cc);
  hipLaunchKernelGGL(fused_conv_gemm_kernel, dim3(B_ * H_ + 1), dim3(512), 0, stream,
                     img, conv_w, conv_b, flatb, Mb, cc, zbuf);
  hipLaunchKernelGGL(gather_kernel, dim3(NOUT_ / 64), dim3(256), 0, stream,
                     xi, yi, flatb, zbuf, out);
}

// Round 13
// 80.782 us; speedup vs baseline: 1.1215x; 1.0859x over previous
//
#include <hip/hip_runtime.h>
#include <hip/hip_bf16.h>
#include <math.h>

#define B_ 8
#define H_ 128
#define W_ 128
#define C_ 3
#define D_ 132
#define HW_ (H_*W_)            // 16384
#define RPB_ (HW_+1)           // 16385 rows per batch (incl. zero row)
#define NROWS_ (B_*RPB_)       // 131080
#define AROWS_ 131136
#define FSTRIDE_ 136           // LDS As row stride (elems)
#define MSTRIDE_ 168           // M row stride
#define MROWS_ 136
#define MELEMS_ (MROWS_*MSTRIDE_)   // 22848 real elems
#define MALLOC_ 23040               // padded to 45 KiB
#define NK_ 65536
#define NOUT_ (B_*NK_)         // 524288

typedef __attribute__((ext_vector_type(8))) short short8v;
typedef __attribute__((ext_vector_type(8))) unsigned short ushort8v;
typedef __attribute__((ext_vector_type(4))) float f32x4;

#define GLOAD16(gp, lp) __builtin_amdgcn_global_load_lds( \
  (const __attribute__((address_space(1))) unsigned int*)(gp), \
  (__attribute__((address_space(3))) unsigned int*)(void*)(lp), 16, 0, 0)

__device__ inline float bf2f(unsigned short u) {
  return __uint_as_float(((unsigned)u) << 16);
}
__device__ inline unsigned short f2bf(float f) {
  __hip_bfloat16 hb = __float2bfloat16(f);
  return *(unsigned short*)&hb;
}

// ---------------------------------------------------------------------------
// K0: M_bf16 [136][168]: a<132 -> Ks^T Qs; a==132 -> u; a==133 -> v; else 0.
// Cols >=132 zero; pad to 23040 zero. c = ks_b . qs_b.
// ---------------------------------------------------------------------------
__global__ __launch_bounds__(512) void prep_kernel(
    const float* __restrict__ ks_w, const float* __restrict__ ks_b,
    const float* __restrict__ qs_w, const float* __restrict__ qs_b,
    unsigned short* __restrict__ Mb, float* __restrict__ cc) {
  int idx = blockIdx.x * 512 + threadIdx.x;
  if (idx >= MALLOC_) return;
  float val = 0.f;
  if (idx < MELEMS_) {
    int a = idx / MSTRIDE_;
    int k = idx - a * MSTRIDE_;
    if (k < D_) {
      if (a < D_) {
        for (int o = 0; o < D_; ++o)
          val = fmaf(ks_w[o * D_ + a], qs_w[o * D_ + k], val);
      } else if (a == 132) {
        for (int o = 0; o < D_; ++o)
          val = fmaf(qs_b[o], ks_w[o * D_ + k], val);
      } else if (a == 133) {
        for (int o = 0; o < D_; ++o)
          val = fmaf(ks_b[o], qs_w[o * D_ + k], val);
      }
    }
  }
  Mb[idx] = f2bf(val);
  if (idx == 0) {
    float s = 0.f;
    for (int o = 0; o < D_; ++o) s = fmaf(ks_b[o], qs_b[o], s);
    cc[0] = s;
  }
}

// ---------------------------------------------------------------------------
// conv helper: one (d, w0) item -> 16 conv outputs + partial ssq
// ---------------------------------------------------------------------------
__device__ __forceinline__ float conv_item16(
    const float* __restrict__ in_s, const float* __restrict__ w_s,
    float bias, int d, int w0, float* acc) {
  float wt[27];
#pragma unroll
  for (int j = 0; j < 27; ++j) wt[j] = w_s[d * 27 + j];
#pragma unroll
  for (int i = 0; i < 16; ++i) acc[i] = bias;
#pragma unroll
  for (int ck = 0; ck < 9; ++ck) {
    const float4* p4 = (const float4*)(in_s + ck * 132);
    float v[20];
#pragma unroll
    for (int j = 0; j < 5; ++j) {
      float4 t4 = p4[(w0 >> 2) + j];   // wave-broadcast reads
      v[4 * j + 0] = t4.x; v[4 * j + 1] = t4.y;
      v[4 * j + 2] = t4.z; v[4 * j + 3] = t4.w;
    }
#pragma unroll
    for (int i = 0; i < 16; ++i) {
      float a0 = fmaf(v[i], wt[ck * 3 + 0], acc[i]);
      float a1 = fmaf(v[i + 1], wt[ck * 3 + 1], a0);
      acc[i] = fmaf(v[i + 2], wt[ck * 3 + 2], a1);
    }
  }
  float ssq = 0.f;
#pragma unroll
  for (int i = 0; i < 16; ++i) ssq = fmaf(acc[i], acc[i], ssq);
  return ssq;
}

// ---------------------------------------------------------------------------
// K1 fused conv+gemm. Output layout is now SPLIT:
//   fmain[row][128] (256 B aligned, 2 cache lines)  ft[row][8] = [f128..131,1,su,0,0]
//   zmain[row][128]                                  zt[row][8] = [z128..131,sv+c,1,0,0]
// Phases: A conv+norm -> regs; B f -> As (LDS); C1 memcpy As->fmain + save
// f-tails to regs + MFMA; C2 z->As, su->su_s (LDS, overlays dead nscale);
// D memcpy As->zmain + assemble ft/zt.
// LDS: Ms 46080 + nscale/su_s 528 + un 34880 = 81488 <= 81920 -> 2 blocks/CU.
// ---------------------------------------------------------------------------
__global__ __launch_bounds__(512, 4) void fused_conv_gemm_kernel(
    const float* __restrict__ img, const float* __restrict__ cw,
    const float* __restrict__ cb, unsigned short* __restrict__ fmain,
    unsigned short* __restrict__ ft, const unsigned short* __restrict__ Mb,
    const float* __restrict__ cc, unsigned short* __restrict__ zmain,
    unsigned short* __restrict__ zt) {
  int bid = blockIdx.x;
  int tid = threadIdx.x;

  if (bid == B_ * H_) {
    // zero row 16384 of every batch
    float cval = cc[0];
    for (int i = tid; i < B_ * 128; i += 512) {
      int b = i >> 7, c = i & 127;
      size_t r = (size_t)b * RPB_ + HW_;
      fmain[r * 128 + c] = 0;
      zmain[r * 128 + c] = 0;
    }
    if (tid < B_) {
      size_t r = (size_t)tid * RPB_ + HW_;
      ushort8v f8 = {0, 0, 0, 0, 0x3F80, 0, 0, 0};          // [0,0,0,0,1,su=0,0,0]
      *(ushort8v*)(ft + r * 8) = f8;
      ushort8v z8 = {0, 0, 0, 0, f2bf(cval), 0x3F80, 0, 0}; // [0..,sv+c=c,1,0,0]
      *(ushort8v*)(zt + r * 8) = z8;
    }
    return;
  }

  int wave = tid >> 6, lane = tid & 63;
  __shared__ __align__(16) unsigned short Ms[MALLOC_];   // 46080 B
  __shared__ __align__(16) float nscale[132];            // 528 B; su_s overlay
  __shared__ __align__(16) char un[34880];               // union region
  float* in_s = (float*)un;            // 9*132
  float* w_s  = in_s + 9 * 132;        // 132*27
  float* b_s  = w_s + 132 * 27;        // 132
  float* parts = b_s + 132;            // 8*132
  unsigned short* As = (unsigned short*)un;  // [128][136] + 32 pad shorts
  unsigned short* su_s = (unsigned short*)nscale;  // after phase B

  // stage M (45 KiB) - drained by the phase-A barrier
  for (int ch = wave; ch < 45; ch += 8)
    GLOAD16(Mb + (size_t)ch * 512 + lane * 8, Ms + ch * 512);

  int b = bid >> 7, h = bid & 127;
  for (int i = tid; i < 9 * 132; i += 512) {
    int ck = i / 132, x = i - ck * 132;
    int c = ck / 3, kh = ck - c * 3;
    int hh = h + kh - 1, ww = x - 1;
    float val = 0.f;
    if (x >= 1 && x <= 128 && hh >= 0 && hh < H_)
      val = img[((size_t)(b * C_ + c) * H_ + hh) * W_ + ww];
    in_s[i] = val;
  }
  for (int i = tid; i < D_ * 27; i += 512) w_s[i] = cw[i];
  if (tid < D_) b_s[tid] = cb[tid];
  __syncthreads();

  // phase A: conv. Items {tid, tid+512, tid+1024 if tid<32}, 16-wide each.
  float acc0[16], acc1[16], acc2[16];
  int i0 = tid, i1 = tid + 512;
  int wg0 = i0 / 132, dd0 = i0 - wg0 * 132;
  int wg1 = i1 / 132, dd1 = i1 - wg1 * 132;
  parts[wg0 * 132 + dd0] = conv_item16(in_s, w_s, b_s[dd0], dd0, wg0 * 16, acc0);
  parts[wg1 * 132 + dd1] = conv_item16(in_s, w_s, b_s[dd1], dd1, wg1 * 16, acc1);
  int dd2 = 0;
  if (tid < 32) {
    dd2 = 100 + tid;
    parts[7 * 132 + dd2] = conv_item16(in_s, w_s, b_s[dd2], dd2, 112, acc2);
  }
  __syncthreads();
  if (tid < 132) {
    float s = 0.f;
#pragma unroll
    for (int rr = 0; rr < 8; ++rr) s += parts[rr * 132 + tid];
    nscale[tid] = 1.f / fmaxf(sqrtf(s), 1e-12f);
  }
  __syncthreads();  // conv scratch dead; As overlay begins

  // phase B: write f (bf16) into As (LDS only)
  {
    float sc = nscale[dd0];
#pragma unroll
    for (int i = 0; i < 16; ++i)
      As[(wg0 * 16 + i) * FSTRIDE_ + dd0] = f2bf(acc0[i] * sc);
    sc = nscale[dd1];
#pragma unroll
    for (int i = 0; i < 16; ++i)
      As[(wg1 * 16 + i) * FSTRIDE_ + dd1] = f2bf(acc1[i] * sc);
  }
  if (tid < 32) {
    float sc = nscale[dd2];
#pragma unroll
    for (int i = 0; i < 16; ++i)
      As[(112 + i) * FSTRIDE_ + dd2] = f2bf(acc2[i] * sc);
  }
  if (tid < 128) {  // As row tails: cols 132..135 = [1.0, 0, 0, 0]
    uint2 tv; tv.x = 0x3F80u; tv.y = 0u;
    *(uint2*)&As[tid * FSTRIDE_ + 132] = tv;
  }
  if (tid < 32) As[128 * FSTRIDE_ + tid] = 0;  // wrap pad for K-slice 5
  __syncthreads();  // As = flat tile; nscale now dead -> su_s overlay OK after this

  // phase C1: memcpy As main -> fmain; save f-tails; MFMA (reads only)
  size_t rowbase = (size_t)b * RPB_ + (size_t)h * W_;
  unsigned short* fmb = fmain + rowbase * 128;
  for (int i2 = tid; i2 < 2048; i2 += 512) {
    int r = i2 >> 4, c8 = i2 & 15;
    *(ushort8v*)(fmb + r * 128 + c8 * 8) = *(const ushort8v*)(As + r * FSTRIDE_ + c8 * 8);
  }
  uint2 ftl = {0, 0};
  if (tid < 128) ftl = *(const uint2*)&As[tid * FSTRIDE_ + 128];  // f128..131

  int c15 = lane & 15, kg = lane >> 4;
  const unsigned short* arow = As + (wave * 16 + c15) * FSTRIDE_ + kg * 8;
  const unsigned short* brow = Ms + c15 * MSTRIDE_ + kg * 8;
  f32x4 acc[9] = {};
#pragma unroll
  for (int ks = 0; ks < 5; ++ks) {
    short8v af = *(const short8v*)(arow + ks * 32);
#pragma unroll
    for (int ct = 0; ct < 9; ++ct) {
      short8v bf = *(const short8v*)(brow + ct * 16 * MSTRIDE_ + ks * 32);
      acc[ct] = __builtin_amdgcn_mfma_f32_16x16x32_bf16(af, bf, acc[ct], 0, 0, 0);
    }
  }
  __syncthreads();  // all As reads retired; fmain stores drained

  // phase C2: overwrite OWN wave's 16 As rows with z_ext; su -> su_s (LDS)
  float cval = cc[0];
  int r0 = wave * 16 + kg * 4;
#pragma unroll
  for (int ct = 0; ct < 9; ++ct) {
    int col = ct * 16 + c15;
#pragma unroll
    for (int j = 0; j < 4; ++j) {
      int r = r0 + j;
      if (col < D_)            As[r * FSTRIDE_ + col] = f2bf(acc[ct][j]);
      else if (col == 132)     su_s[r] = f2bf(acc[ct][j]);                   // su
      else if (col == 133)     As[r * FSTRIDE_ + 132] = f2bf(acc[ct][j] + cval); // sv+c
      else if (col == 134)     As[r * FSTRIDE_ + 133] = 0x3F80;              // 1.0
      else if (col == 135)     As[r * FSTRIDE_ + 134] = 0;
      else if (col == 136)     As[r * FSTRIDE_ + 135] = 0;
    }
  }
  __syncthreads();  // z_ext tile complete in As; su_s complete

  // phase D: memcpy As main -> zmain; assemble zt / ft
  unsigned short* zmb = zmain + rowbase * 128;
  for (int i2 = tid; i2 < 2048; i2 += 512) {
    int r = i2 >> 4, c8 = i2 & 15;
    *(ushort8v*)(zmb + r * 128 + c8 * 8) = *(const ushort8v*)(As + r * FSTRIDE_ + c8 * 8);
  }
  if (tid < 128) {
    // zt[r] = As[r][128..135] = [z128..131, sv+c, 1.0, 0, 0]
    *(ushort8v*)(zt + (rowbase + tid) * 8) = *(const ushort8v*)(As + tid * FSTRIDE_ + 128);
    // ft[r] = [f128..131, 1.0, su, 0, 0]
    ushort8v f8;
    f8[0] = (unsigned short)(ftl.x & 0xFFFFu);
    f8[1] = (unsigned short)(ftl.x >> 16);
    f8[2] = (unsigned short)(ftl.y & 0xFFFFu);
    f8[3] = (unsigned short)(ftl.y >> 16);
    f8[4] = 0x3F80;
    f8[5] = su_s[tid];
    f8[6] = 0;
    f8[7] = 0;
    *(ushort8v*)(ft + (rowbase + tid) * 8) = f8;
  }
}

// ---------------------------------------------------------------------------
// K3: gather + dot, split-row layout. XCD batch-affinity (b = blockIdx & 7),
// 2 outputs/thread within the same batch. Main rows = 2 aligned cache lines;
// tail arrays (16 B/row) are L2-resident.
// ---------------------------------------------------------------------------
__global__ __launch_bounds__(256) void gather_kernel(
    const int* __restrict__ xi, const int* __restrict__ yi,
    const unsigned short* __restrict__ fmain, const unsigned short* __restrict__ ft,
    const unsigned short* __restrict__ zmain, const unsigned short* __restrict__ zt,
    float* __restrict__ out) {
  const float scale = 0.08703882797784892f;  // 132^-0.5
  int bi = blockIdx.x;                 // [0, 8192)
  int b = bi & 7;
  int chunk = bi >> 3;                 // [0, 1024)
  int lane = threadIdx.x & 7;
  int rem1 = chunk * 32 + (threadIdx.x >> 3);
  int rem2 = rem1 + 32768;             // same batch

  size_t ib1 = (size_t)b * NK_ + rem1;
  size_t ib2 = (size_t)b * NK_ + rem2;
  int x1 = xi[ib1], y1 = yi[ib1];
  int x2 = xi[ib2], y2 = yi[ib2];
  size_t bbase = (size_t)b * RPB_;
  const unsigned short* fx1 = fmain + (bbase + x1) * 128;
  const unsigned short* zy1 = zmain + (bbase + y1) * 128;
  const unsigned short* fx2 = fmain + (bbase + x2) * 128;
  const unsigned short* zy2 = zmain + (bbase + y2) * 128;

  int e0 = lane * 16;
  ushort8v a10 = *(const ushort8v*)(fx1 + e0);
  ushort8v a11 = *(const ushort8v*)(fx1 + e0 + 8);
  ushort8v z10 = *(const ushort8v*)(zy1 + e0);
  ushort8v z11 = *(const ushort8v*)(zy1 + e0 + 8);
  ushort8v a20 = *(const ushort8v*)(fx2 + e0);
  ushort8v a21 = *(const ushort8v*)(fx2 + e0 + 8);
  ushort8v z20 = *(const ushort8v*)(zy2 + e0);
  ushort8v z21 = *(const ushort8v*)(zy2 + e0 + 8);
  ushort8v a1t, z1t, a2t, z2t;
  if (lane == 0) {   // 16-B tails (L2-resident)
    a1t = *(const ushort8v*)(ft + (bbase + x1) * 8);
    z1t = *(const ushort8v*)(zt + (bbase + y1) * 8);
    a2t = *(const ushort8v*)(ft + (bbase + x2) * 8);
    z2t = *(const ushort8v*)(zt + (bbase + y2) * 8);
  }

  float acc1 = 0.f, acc2 = 0.f;
#pragma unroll
  for (int t = 0; t < 8; ++t) {
    acc1 = fmaf(bf2f(a10[t]), bf2f(z10[t]), acc1);
    acc2 = fmaf(bf2f(a20[t]), bf2f(z20[t]), acc2);
  }
#pragma unroll
  for (int t = 0; t < 8; ++t) {
    acc1 = fmaf(bf2f(a11[t]), bf2f(z11[t]), acc1);
    acc2 = fmaf(bf2f(a21[t]), bf2f(z21[t]), acc2);
  }
  if (lane == 0) {  // tails: f-tail·z-tail + (1)(sv+c) + (su)(1)
#pragma unroll
    for (int t = 0; t < 8; ++t) {
      acc1 = fmaf(bf2f(a1t[t]), bf2f(z1t[t]), acc1);
      acc2 = fmaf(bf2f(a2t[t]), bf2f(z2t[t]), acc2);
    }
  }
  acc1 += __shfl_xor(acc1, 1);
  acc2 += __shfl_xor(acc2, 1);
  acc1 += __shfl_xor(acc1, 2);
  acc2 += __shfl_xor(acc2, 2);
  acc1 += __shfl_xor(acc1, 4);
  acc2 += __shfl_xor(acc2, 4);
  if (lane == 0) {
    out[((size_t)b << 16) | rem1] = acc1 * scale;
    out[((size_t)b << 16) | rem2] = acc2 * scale;
  }
}

// ---------------------------------------------------------------------------
extern "C" void kernel_launch(void* const* d_in, const int* in_sizes, int n_in,
                              void* d_out, int out_size, void* d_ws, size_t ws_size,
                              hipStream_t stream) {
  const int* indices  = (const int*)d_in[0];
  const float* img    = (const float*)d_in[1];
  const float* conv_w = (const float*)d_in[2];
  const float* conv_b = (const float*)d_in[3];
  const float* ks_w   = (const float*)d_in[4];
  const float* ks_b   = (const float*)d_in[5];
  const float* qs_w   = (const float*)d_in[6];
  const float* qs_b   = (const float*)d_in[7];
  float* out = (float*)d_out;

  // workspace layout (~71.4 MB)
  char* w = (char*)d_ws;
  unsigned short* fmain = (unsigned short*)w;                   // AROWS_*128
  size_t off = (size_t)AROWS_ * 128 * 2;                        // 33,570,816
  unsigned short* zmain = (unsigned short*)(w + off); off += (size_t)AROWS_ * 128 * 2;
  unsigned short* ftl = (unsigned short*)(w + off);   off += (size_t)AROWS_ * 8 * 2;
  unsigned short* ztl = (unsigned short*)(w + off);   off += (size_t)AROWS_ * 8 * 2;
  unsigned short* Mb = (unsigned short*)(w + off);    off += MALLOC_ * 2;
  float* cc = (float*)(w + off);

  const int* xi = indices + (size_t)B_ * NK_;      // indices[1]
  const int* yi = indices + (size_t)2 * B_ * NK_;  // indices[2]

  hipLaunchKernelGGL(prep_kernel, dim3(MALLOC_ / 512), dim3(512), 0, stream,
                     ks_w, ks_b, qs_w, qs_b, Mb, cc);
  hipLaunchKernelGGL(fused_conv_gemm_kernel, dim3(B_ * H_ + 1), dim3(512), 0, stream,
                     img, conv_w, conv_b, fmain, ftl, Mb, cc, zmain, ztl);
  hipLaunchKernelGGL(gather_kernel, dim3(NOUT_ / 64), dim3(256), 0, stream,
                     xi, yi, fmain, ftl, zmain, ztl, out);
}